// Round 13
// baseline (189.573 us; speedup 1.0000x reference)
//
#include <hip/hip_runtime.h>

#define N_SEQ 4140
#define NP    4160          // padded N (130*32)
#define C_IN  256
#define HEADS 8
#define NT32  130
#define HN    (HEADS * N_SEQ)
#define LOG2E 1.4426950408889634f
#define SCALE2 (0.17677669529663687f * LOG2E)   // (1/sqrt(32)) * log2e

typedef _Float16 f16x8 __attribute__((ext_vector_type(8)));
typedef _Float16 f16x2 __attribute__((ext_vector_type(2)));
typedef float    f32x16 __attribute__((ext_vector_type(16)));

__device__ inline unsigned short f16b(float x) {
    union { _Float16 h; unsigned short s; } c;
    c.h = (_Float16)x;
    return c.s;
}
__device__ inline f16x2 pkrtz(float a, float b) {
    auto r = __builtin_amdgcn_cvt_pkrtz(a, b);   // __fp16 ext_vector(2)
    union { decltype(r) i; f16x2 o; } c;
    c.i = r;
    return c.o;
}
__device__ inline unsigned pkrtz_u(float a, float b) {
    auto r = __builtin_amdgcn_cvt_pkrtz(a, b);
    union { decltype(r) i; unsigned o; } c;
    c.i = r;
    return c.o;
}
__device__ inline void permswap(unsigned &a, unsigned &b) {
    asm volatile("v_permlane32_swap_b32 %0, %1" : "+v"(a), "+v"(b));
}

// ---------------------------------------------------------------------------
// prep: blocks x<130: x[c][n] f32 -> xt[n][c] f16 (zero-pad n>=N_SEQ).
//       blocks x>=130: weights f16 (q_w pre-scaled by SCALE2), lw2 = log_qw*log2e
// grid: (133, 8) x 256
// ---------------------------------------------------------------------------
__global__ __launch_bounds__(256) void prep_kernel(
    const float* __restrict__ x, const float* __restrict__ log_qw,
    const float* __restrict__ q_w, const float* __restrict__ k_w,
    const float* __restrict__ v_w, const float* __restrict__ p_w,
    unsigned short* __restrict__ xt, float* __restrict__ lw2,
    unsigned short* __restrict__ wf, unsigned short* __restrict__ pwf)
{
    if (blockIdx.x < NT32) {
        __shared__ unsigned short tile[32][33];
        const int tx = threadIdx.x & 31, ty = threadIdx.x >> 5;
        const int n0 = blockIdx.x * 32, c0 = blockIdx.y * 32;
#pragma unroll
        for (int i = 0; i < 4; ++i) {
            const int c = c0 + ty * 4 + i;
            const int n = n0 + tx;
            const float v = (n < N_SEQ) ? x[(size_t)c * N_SEQ + n] : 0.f;
            tile[tx][ty * 4 + i] = f16b(v);
        }
        __syncthreads();
#pragma unroll
        for (int i = 0; i < 4; ++i) {
            const int nl = ty * 4 + i;
            xt[(size_t)(n0 + nl) * C_IN + c0 + tx] = tile[nl][tx];
        }
    } else {
        const int bid = (blockIdx.x - NT32) * 8 + blockIdx.y;   // 0..23
        for (int i = bid * 256 + threadIdx.x; i < 262144 + NP; i += 24 * 256) {
            if (i < 65536)        wf[i] = f16b(q_w[i] * SCALE2);
            else if (i < 131072)  wf[i] = f16b(k_w[i - 65536]);
            else if (i < 196608)  wf[i] = f16b(v_w[i - 131072]);
            else if (i < 262144)  pwf[i - 196608] = f16b(p_w[i - 196608]);
            else {
                const int j = i - 262144;
                lw2[j] = (j < N_SEQ) ? log_qw[j] * LOG2E : -1e30f;
            }
        }
    }
}

// ---------------------------------------------------------------------------
// qkv_mfma: one 32x32 output tile per 64-thread block (wave). Dual
// independent K-chains for ILP. q (pre-scaled), k -> [h][n][32] ;
// v -> [((h*130+nt)*32+d)*32+klocal].  grid: 3120 x 64
// ---------------------------------------------------------------------------
__global__ __launch_bounds__(64) void qkv_mfma(
    const unsigned short* __restrict__ xt, const unsigned short* __restrict__ wf,
    const float* __restrict__ q_b, const float* __restrict__ k_b,
    const float* __restrict__ v_b,
    unsigned short* __restrict__ qo, unsigned short* __restrict__ ko,
    unsigned short* __restrict__ vo)
{
    const int lane = threadIdx.x;
    const int col = lane & 31, hi = lane >> 5;
    const int bid = blockIdx.x;                  // 0..3119
    const int ot = bid / NT32, nt = bid % NT32;
    const int n0 = nt * 32;

    if (ot < 16) {
        const unsigned short* arow = xt + (size_t)(n0 + col) * C_IN + hi * 8;
        const unsigned short* brow = wf + (size_t)(ot * 32 + col) * C_IN + hi * 8;
        const float bias = (ot < 8) ? q_b[ot * 32 + col] * SCALE2
                                    : k_b[(ot - 8) * 32 + col];
        f32x16 acc0, acc1;
#pragma unroll
        for (int r = 0; r < 16; ++r) { acc0[r] = bias; acc1[r] = 0.f; }
#pragma unroll
        for (int t = 0; t < 8; ++t) {
            const f16x8 af0 = *(const f16x8*)(const void*)(arow + t * 16);
            const f16x8 bf0 = *(const f16x8*)(const void*)(brow + t * 16);
            const f16x8 af1 = *(const f16x8*)(const void*)(arow + (t + 8) * 16);
            const f16x8 bf1 = *(const f16x8*)(const void*)(brow + (t + 8) * 16);
            acc0 = __builtin_amdgcn_mfma_f32_32x32x16_f16(af0, bf0, acc0, 0, 0, 0);
            acc1 = __builtin_amdgcn_mfma_f32_32x32x16_f16(af1, bf1, acc1, 0, 0, 0);
        }
        unsigned short* dst = (ot < 8) ? qo : ko;
        const int h = ot & 7;
#pragma unroll
        for (int r = 0; r < 16; ++r) {
            const int rl = (r & 3) + 8 * (r >> 2) + 4 * hi;
            dst[(size_t)(h * NP + n0 + rl) * 32 + col] = f16b(acc0[r] + acc1[r]);
        }
    } else {
        const int h = ot - 16;
        const unsigned short* arow = wf + (size_t)(512 + h * 32 + col) * C_IN + hi * 8;
        const unsigned short* brow = xt + (size_t)(n0 + col) * C_IN + hi * 8;
        const float* vb4 = v_b + h * 32 + 4 * hi;
        const float4 c0 = *(const float4*)(vb4);
        const float4 c1 = *(const float4*)(vb4 + 8);
        const float4 c2 = *(const float4*)(vb4 + 16);
        const float4 c3 = *(const float4*)(vb4 + 24);
        f32x16 acc0, acc1;
        acc0[0]=c0.x; acc0[1]=c0.y; acc0[2]=c0.z; acc0[3]=c0.w;
        acc0[4]=c1.x; acc0[5]=c1.y; acc0[6]=c1.z; acc0[7]=c1.w;
        acc0[8]=c2.x; acc0[9]=c2.y; acc0[10]=c2.z; acc0[11]=c2.w;
        acc0[12]=c3.x; acc0[13]=c3.y; acc0[14]=c3.z; acc0[15]=c3.w;
#pragma unroll
        for (int r = 0; r < 16; ++r) acc1[r] = 0.f;
#pragma unroll
        for (int t = 0; t < 8; ++t) {
            const f16x8 af0 = *(const f16x8*)(const void*)(arow + t * 16);
            const f16x8 bf0 = *(const f16x8*)(const void*)(brow + t * 16);
            const f16x8 af1 = *(const f16x8*)(const void*)(arow + (t + 8) * 16);
            const f16x8 bf1 = *(const f16x8*)(const void*)(brow + (t + 8) * 16);
            acc0 = __builtin_amdgcn_mfma_f32_32x32x16_f16(af0, bf0, acc0, 0, 0, 0);
            acc1 = __builtin_amdgcn_mfma_f32_32x32x16_f16(af1, bf1, acc1, 0, 0, 0);
        }
#pragma unroll
        for (int r = 0; r < 16; ++r) {
            const int d = (r & 3) + 8 * (r >> 2) + 4 * hi;
            vo[((size_t)(h * NT32 + nt) * 32 + d) * 32 + col] = f16b(acc0[r] + acc1[r]);
        }
    }
}

// ---------------------------------------------------------------------------
// MFMA flash attention. ONE q-tile per wave (max wave-level TLP), op-diet
// softmax (pre-scaled Q, lw2 C-init, max3 trees, defer-max, pkrtz, fdot2,
// permlane32_swap). Stores NORMALIZED O (o/l) as f16 + (m,l) f32.
// grid: (1040, nz) x 64, 8 waves/SIMD target.
// ---------------------------------------------------------------------------
__global__ __launch_bounds__(64, 8) void attn_mfma_kernel(
    const unsigned short* __restrict__ qb, const unsigned short* __restrict__ kb,
    const unsigned short* __restrict__ vb, const float* __restrict__ lw2,
    float* __restrict__ pm, float* __restrict__ pl,
    unsigned short* __restrict__ pacc, int tiles_per_z)
{
    const int lane = threadIdx.x;
    const int col = lane & 31;
    const int hi = lane >> 5;
    const int job = blockIdx.x;             // 0..1039
    const int h = job / NT32;
    const int qt = job % NT32;
    const int z = blockIdx.y;

    const int qrow = qt * 32 + col;
    const unsigned short* qp = qb + ((size_t)(h * NP + qrow)) * 32 + hi * 8;
    const f16x8 qf0 = *(const f16x8*)(const void*)(qp);
    const f16x8 qf1 = *(const f16x8*)(const void*)(qp + 16);

    f32x16 o;
#pragma unroll
    for (int r = 0; r < 16; ++r) o[r] = 0.f;
    float m = -1e30f, lsum = 0.f;
    const f16x2 one2 = { (_Float16)1.f, (_Float16)1.f };

    const int t0 = z * tiles_per_z;
    const int t1 = min(NT32, t0 + tiles_per_z);
    const unsigned short* kbase = kb + (size_t)h * NP * 32;
    const unsigned short* vbase = vb + (size_t)h * NT32 * 1024;

    for (int t = t0; t < t1; ++t) {
        const int k0 = t * 32;
        const unsigned short* kp = kbase + (size_t)(k0 + col) * 32 + hi * 8;
        const f16x8 ka0 = *(const f16x8*)(const void*)(kp);
        const f16x8 ka1 = *(const f16x8*)(const void*)(kp + 16);
        const unsigned short* vp = vbase + (size_t)t * 1024 + col * 32 + hi * 8;
        const f16x8 va0 = *(const f16x8*)(const void*)(vp);
        const f16x8 va1 = *(const f16x8*)(const void*)(vp + 16);

        const float* lw4 = lw2 + k0 + 4 * hi;
        const float4 w0 = *(const float4*)(lw4);
        const float4 w1 = *(const float4*)(lw4 + 8);
        const float4 w2 = *(const float4*)(lw4 + 16);
        const float4 w3 = *(const float4*)(lw4 + 24);
        f32x16 s;
        s[0]=w0.x; s[1]=w0.y; s[2]=w0.z; s[3]=w0.w;
        s[4]=w1.x; s[5]=w1.y; s[6]=w1.z; s[7]=w1.w;
        s[8]=w2.x; s[9]=w2.y; s[10]=w2.z; s[11]=w2.w;
        s[12]=w3.x; s[13]=w3.y; s[14]=w3.z; s[15]=w3.w;

        s = __builtin_amdgcn_mfma_f32_32x32x16_f16(ka0, qf0, s, 0, 0, 0);
        s = __builtin_amdgcn_mfma_f32_32x32x16_f16(ka1, qf1, s, 0, 0, 0);

        const float x0 = fmaxf(fmaxf(s[0], s[1]), s[2]);
        const float x1 = fmaxf(fmaxf(s[3], s[4]), s[5]);
        const float x2 = fmaxf(fmaxf(s[6], s[7]), s[8]);
        const float x3 = fmaxf(fmaxf(s[9], s[10]), s[11]);
        const float x4 = fmaxf(fmaxf(s[12], s[13]), s[14]);
        const float cmax = fmaxf(fmaxf(fmaxf(x0, x1), x2),
                                 fmaxf(fmaxf(x3, x4), s[15]));

        if (!__all(cmax - m <= 8.0f)) {
            float cw = fmaxf(cmax, __shfl_xor(cmax, 32));
            const float mnew = fmaxf(m, cw);
            const float esc = __builtin_amdgcn_exp2f(m - mnew);
            lsum *= esc;
#pragma unroll
            for (int r = 0; r < 16; ++r) o[r] *= esc;
            m = mnew;
        }

        float p[16];
#pragma unroll
        for (int r = 0; r < 16; ++r) p[r] = __builtin_amdgcn_exp2f(s[r] - m);

        union PK { f16x2 h[4]; unsigned u[4]; f16x8 v; };
        PK k0p, k1p;
        k0p.h[0] = pkrtz(p[0], p[1]);
        k0p.h[1] = pkrtz(p[2], p[3]);
        k0p.h[2] = pkrtz(p[4], p[5]);
        k0p.h[3] = pkrtz(p[6], p[7]);
        k1p.h[0] = pkrtz(p[8], p[9]);
        k1p.h[1] = pkrtz(p[10], p[11]);
        k1p.h[2] = pkrtz(p[12], p[13]);
        k1p.h[3] = pkrtz(p[14], p[15]);
        float sa = __builtin_amdgcn_fdot2(k0p.h[0], one2, 0.f, false);
        float sb = __builtin_amdgcn_fdot2(k0p.h[1], one2, 0.f, false);
        sa = __builtin_amdgcn_fdot2(k0p.h[2], one2, sa, false);
        sb = __builtin_amdgcn_fdot2(k0p.h[3], one2, sb, false);
        sa = __builtin_amdgcn_fdot2(k1p.h[0], one2, sa, false);
        sb = __builtin_amdgcn_fdot2(k1p.h[1], one2, sb, false);
        sa = __builtin_amdgcn_fdot2(k1p.h[2], one2, sa, false);
        sb = __builtin_amdgcn_fdot2(k1p.h[3], one2, sb, false);
        lsum += sa + sb;
        permswap(k0p.u[0], k0p.u[2]);
        permswap(k0p.u[1], k0p.u[3]);
        o = __builtin_amdgcn_mfma_f32_32x32x16_f16(va0, k0p.v, o, 0, 0, 0);
        permswap(k1p.u[0], k1p.u[2]);
        permswap(k1p.u[1], k1p.u[3]);
        o = __builtin_amdgcn_mfma_f32_32x32x16_f16(va1, k1p.v, o, 0, 0, 0);
    }

    lsum += __shfl_xor(lsum, 32);   // full row sum for q=col

    if (qrow < N_SEQ) {
        const size_t qi = (size_t)h * N_SEQ + qrow;
        if (hi == 0) {
            pm[(size_t)z * HN + qi] = m;
            pl[(size_t)z * HN + qi] = lsum;
        }
        const float inv = 1.0f / lsum;
        // normalized O -> f16; d-groups of 4 consecutive (8B stores)
        unsigned short* pa = pacc + ((size_t)z * HN + qi) * 32;
#pragma unroll
        for (int g = 0; g < 4; ++g) {
            const int d0 = g * 8 + 4 * hi;          // start d of this group
            uint2 w;
            w.x = pkrtz_u(o[g * 4 + 0] * inv, o[g * 4 + 1] * inv);
            w.y = pkrtz_u(o[g * 4 + 2] * inv, o[g * 4 + 3] * inv);
            *(uint2*)(pa + d0) = w;
        }
    }
}

// ---------------------------------------------------------------------------
// Merge normalized f16 partials: out = sum_z w_z*o_z / sum_z w_z,
// w_z = exp2(m_z - mg) * l_z.  4 threads per query (8 d's each).
// grid: ceil(HN*4/256) x 256
// ---------------------------------------------------------------------------
__global__ __launch_bounds__(256) void merge_kernel(
    const float* __restrict__ pm, const float* __restrict__ pl,
    const unsigned short* __restrict__ pacc, unsigned short* __restrict__ at_t,
    int nz)
{
    const int gid = blockIdx.x * 256 + threadIdx.x;
    if (gid >= HN * 4) return;
    const int idx = gid >> 2;
    const int sub = gid & 3;
    const int h = idx / N_SEQ;
    const int n = idx - h * N_SEQ;

    float mg = pm[idx];
    for (int zz = 1; zz < nz; ++zz) mg = fmaxf(mg, pm[(size_t)zz * HN + idx]);

    float lg = 0.f;
    float acc[8];
#pragma unroll
    for (int d = 0; d < 8; ++d) acc[d] = 0.f;
    for (int zz = 0; zz < nz; ++zz) {
        const float w = exp2f(pm[(size_t)zz * HN + idx] - mg)
                      * pl[(size_t)zz * HN + idx];
        lg += w;
        const unsigned short* pa = pacc + ((size_t)zz * HN + idx) * 32 + sub * 8;
        union { uint4 u; _Float16 hh[8]; } ld;
        ld.u = *(const uint4*)pa;
#pragma unroll
        for (int d = 0; d < 8; ++d) acc[d] = fmaf(w, (float)ld.hh[d], acc[d]);
    }
    const float inv = 1.0f / lg;
    union { unsigned short s[8]; uint4 u; } ph;
#pragma unroll
    for (int d = 0; d < 8; ++d) ph.s[d] = f16b(acc[d] * inv);
    *(uint4*)(at_t + (size_t)n * C_IN + h * 32 + sub * 8) = ph.u;
}

// ---------------------------------------------------------------------------
// proj_mfma: out[oc][n] = p_w . at + p_b. Split-K dual chain. f32 out.
// grid: 1040 x 64 (one tile per wave)
// ---------------------------------------------------------------------------
__global__ __launch_bounds__(64) void proj_mfma(
    const unsigned short* __restrict__ at_t, const unsigned short* __restrict__ pwf,
    const float* __restrict__ p_b, float* __restrict__ out)
{
    const int lane = threadIdx.x;
    const int col = lane & 31, hi = lane >> 5;
    const int tile = blockIdx.x;                 // 0..1039
    const int ot = tile / NT32, nt = tile % NT32;
    const int n0 = nt * 32;

    const unsigned short* arow = pwf + (size_t)(ot * 32 + col) * C_IN + hi * 8;
    const unsigned short* brow = at_t + (size_t)(n0 + col) * C_IN + hi * 8;

    const float* pb4 = p_b + ot * 32 + 4 * hi;
    const float4 c0 = *(const float4*)(pb4);
    const float4 c1 = *(const float4*)(pb4 + 8);
    const float4 c2 = *(const float4*)(pb4 + 16);
    const float4 c3 = *(const float4*)(pb4 + 24);
    f32x16 acca, accb;
    acca[0]=c0.x; acca[1]=c0.y; acca[2]=c0.z; acca[3]=c0.w;
    acca[4]=c1.x; acca[5]=c1.y; acca[6]=c1.z; acca[7]=c1.w;
    acca[8]=c2.x; acca[9]=c2.y; acca[10]=c2.z; acca[11]=c2.w;
    acca[12]=c3.x; acca[13]=c3.y; acca[14]=c3.z; acca[15]=c3.w;
#pragma unroll
    for (int r = 0; r < 16; ++r) accb[r] = 0.f;

#pragma unroll
    for (int t = 0; t < 8; ++t) {
        const f16x8 afa = *(const f16x8*)(const void*)(arow + t * 16);
        const f16x8 bfa = *(const f16x8*)(const void*)(brow + t * 16);
        const f16x8 afb = *(const f16x8*)(const void*)(arow + (t + 8) * 16);
        const f16x8 bfb = *(const f16x8*)(const void*)(brow + (t + 8) * 16);
        acca = __builtin_amdgcn_mfma_f32_32x32x16_f16(afa, bfa, acca, 0, 0, 0);
        accb = __builtin_amdgcn_mfma_f32_32x32x16_f16(afb, bfb, accb, 0, 0, 0);
    }

    const int n = n0 + col;
    if (n < N_SEQ) {
#pragma unroll
        for (int r = 0; r < 16; ++r) {
            const int oc = ot * 32 + (r & 3) + 8 * (r >> 2) + 4 * hi;
            out[(size_t)oc * N_SEQ + n] = acca[r] + accb[r];
        }
    }
}

extern "C" void kernel_launch(void* const* d_in, const int* in_sizes, int n_in,
                              void* d_out, int out_size, void* d_ws, size_t ws_size,
                              hipStream_t stream) {
    const float* query  = (const float*)d_in[0];
    const float* q_w    = (const float*)d_in[1];
    const float* q_b    = (const float*)d_in[2];
    const float* k_w    = (const float*)d_in[3];
    const float* k_b    = (const float*)d_in[4];
    const float* v_w    = (const float*)d_in[5];
    const float* v_b    = (const float*)d_in[6];
    const float* p_w    = (const float*)d_in[7];
    const float* p_b    = (const float*)d_in[8];
    const float* log_qw = (const float*)d_in[9];

    const size_t HNP32 = (size_t)HEADS * NP * 32;    // 1,064,960

    unsigned short* xt  = (unsigned short*)d_ws;     // NP*256
    unsigned short* qb  = xt + (size_t)NP * C_IN;    // HNP32
    unsigned short* kb  = qb + HNP32;
    unsigned short* vb  = kb + HNP32;                // tiled V
    unsigned short* wf  = vb + HNP32;                // 768*256
    unsigned short* pwf = wf + 768 * 256;            // 256*256
    float* lw2 = (float*)(pwf + 256 * 256);          // NP
    float* pm  = lw2 + NP;
    unsigned short* at_t = qb;                       // alias: qb dead after attn

    const size_t base_bytes = (size_t)((char*)pm - (char*)d_ws);
    // per z: pm + pl (f32) + 32 f16 pacc = 8 + 64 bytes per query
    const size_t per_z = (size_t)HN * 72;
    int nz = 1;
    if      (ws_size >= base_bytes + 8 * per_z) nz = 8;
    else if (ws_size >= base_bytes + 4 * per_z) nz = 4;
    else if (ws_size >= base_bytes + 2 * per_z) nz = 2;
    const int tiles_per_z = (NT32 + nz - 1) / nz;

    float* pl = pm + (size_t)nz * HN;
    unsigned short* pacc = (unsigned short*)(pl + (size_t)nz * HN);

    prep_kernel<<<dim3(NT32 + 3, 8), 256, 0, stream>>>(
        query, log_qw, q_w, k_w, v_w, p_w, xt, lw2, wf, pwf);

    qkv_mfma<<<dim3(3120), 64, 0, stream>>>(
        xt, wf, q_b, k_b, v_b, qb, kb, vb);

    attn_mfma_kernel<<<dim3(1040, nz), 64, 0, stream>>>(
        qb, kb, vb, lw2, pm, pl, pacc, tiles_per_z);

    merge_kernel<<<dim3((HN * 4 + 255) / 256), 256, 0, stream>>>(
        pm, pl, pacc, at_t, nz);

    proj_mfma<<<dim3(1040), 64, 0, stream>>>(
        at_t, pwf, p_b, (float*)d_out);
}